// Round 8
// baseline (157.227 us; speedup 1.0000x reference)
//
#include <hip/hip_runtime.h>

#define KC 512
#define NR 65536

// d_out layout (floats), reference return order:
// quantize_st[4194304], diff[1], embed_ind[65536], embed_new[32768],
// new_cluster_size[512], new_embed_avg[32768]
#define OFF_Q     0
#define OFF_DIFF  4194304
#define OFF_IND   4194305
#define OFF_ENEW  4259841
#define OFF_NCS   4292609
#define OFF_NAVG  4293121

// ws layout (floats)
#define WS_ET    0        // 32768: embed transposed [K][D]
#define WS_C     32768    // 512:   0.5*||e_k||^2
#define WS_CNT   33280    // 512:   one-hot counts
#define WS_ESUM  33792    // 32768: embed_sum transposed [K][D]
#define WS_DIFF  66560    // 1:     sum of squared diff
#define WS_NTOT  66561    // 1:     sum of new_cluster_size

// Prep: transpose embed [D][K] -> Et [K][D], code-norm bias, zero accumulators.
__global__ __launch_bounds__(256) void k_prep(const float* __restrict__ embed,
                                              float* __restrict__ ws) {
    int i = blockIdx.x * 256 + threadIdx.x;
    if (i < 512 + 32768 + 2) ws[WS_CNT + i] = 0.0f;   // counts, esum, diff, ntot
    if (i < 32768) {
        int k = i >> 6, d = i & 63;
        ws[WS_ET + i] = embed[d * KC + k];
    }
    if (i < 512) {
        float s = 0.0f;
        #pragma unroll
        for (int d = 0; d < 64; ++d) { float e = embed[d * KC + i]; s = fmaf(e, e, s); }
        ws[WS_C + i] = 0.5f * s;
    }
}

// Persistent register-tiled kernel. Grid = 256 blocks (1/CU), 512 thr = 8 waves.
// E^T (128 KB = 8192 float4) staged ONCE per block into XOR-swizzled LDS
// (16 it x 512 thr — round 7 staged only half!); block loops 4 groups of 64
// rows. Lane l owns codes {l+64j}; wave owns 8 rows/group. acc[8][8]: per
// dq-step = 8 ds_read_b128 (E, 8x reuse) + 8 s_load_dwordx4 (x, wave-uniform,
// 32x reuse) + 256 v_fma. Per-code FP order identical to rounds 2-6.
__global__ __launch_bounds__(512) void k_main(const float* __restrict__ input,
                                              const float* __restrict__ Et,   // [512][64]
                                              const float* __restrict__ c,
                                              float* __restrict__ out,
                                              float* __restrict__ counts,
                                              float* __restrict__ esum,
                                              float* __restrict__ diffsum) {
    __shared__ float4 EK4[8192];   // 128 KB: row k at [k*16], slot s stored at s^(k&15)

    const int t    = threadIdx.x;
    const int lane = t & 63;
    const int wave = __builtin_amdgcn_readfirstlane(t >> 6);  // 0..7, uniform
    const int sw   = lane & 15;

    // Stage swizzled E^T: ALL 8192 float4s (16 x 512).
    {
        const float4* Et4 = reinterpret_cast<const float4*>(Et);
        #pragma unroll
        for (int it = 0; it < 16; ++it) {
            int i = t + it * 512;
            int k = i >> 4, s = i & 15;
            EK4[k * 16 + (s ^ (k & 15))] = Et4[i];
        }
    }
    __syncthreads();

    // Per-lane code bias, hoisted across groups: codes c_j = lane + 64j.
    float negc[8];
    #pragma unroll
    for (int j = 0; j < 8; ++j) negc[j] = -c[lane + 64 * j];

    for (int g = 0; g < 4; ++g) {
        const int row0 = blockIdx.x * 256 + g * 64 + wave * 8;

        float acc[8][8];
        #pragma unroll
        for (int r = 0; r < 8; ++r)
            #pragma unroll
            for (int j = 0; j < 8; ++j) acc[r][j] = negc[j];

        for (int dq = 0; dq < 16; ++dq) {
            // x: wave-uniform addresses -> s_load_dwordx4 (scalar pipe)
            float4 xr[8];
            #pragma unroll
            for (int r = 0; r < 8; ++r)
                xr[r] = *reinterpret_cast<const float4*>(input + (size_t)(row0 + r) * 64 + dq * 4);
            #pragma unroll
            for (int j = 0; j < 8; ++j) {
                float4 e4 = EK4[(lane + 64 * j) * 16 + (dq ^ sw)];  // ds_read_b128
                #pragma unroll
                for (int r = 0; r < 8; ++r) {
                    acc[r][j] = fmaf(xr[r].x, e4.x, acc[r][j]);
                    acc[r][j] = fmaf(xr[r].y, e4.y, acc[r][j]);
                    acc[r][j] = fmaf(xr[r].z, e4.z, acc[r][j]);
                    acc[r][j] = fmaf(xr[r].w, e4.w, acc[r][j]);
                }
            }
        }

        // Per-row argmax (j ascending = k ascending; cross-lane lowest-k tie),
        // fused with epilogue: quantize gather, EMA scatter, diff partials.
        float dsum = 0.0f;
        #pragma unroll
        for (int r = 0; r < 8; ++r) {
            float b = acc[r][0]; int bk = lane;
            #pragma unroll
            for (int j = 1; j < 8; ++j) {
                int cc = lane + 64 * j;
                if (acc[r][j] > b) { b = acc[r][j]; bk = cc; }
            }
            #pragma unroll
            for (int off = 1; off < 64; off <<= 1) {
                float vv = __shfl_xor(b, off);
                int   kk = __shfl_xor(bk, off);
                if (vv > b || (vv == b && kk < bk)) { b = vv; bk = kk; }
            }
            const int row = row0 + r;
            float e = Et[(size_t)bk * 64 + lane];          // 256 B coalesced gather
            out[OFF_Q + (size_t)row * 64 + lane] = e;
            float xv = input[(size_t)row * 64 + lane];
            atomicAdd(&esum[bk * 64 + lane], xv);
            float xs = xv * xv;
            #pragma unroll
            for (int off2 = 32; off2 > 0; off2 >>= 1) xs += __shfl_down(xs, off2);
            if (lane == 0) {
                out[OFF_IND + row] = (float)bk;
                atomicAdd(&counts[bk], 1.0f);
                dsum += xs - 2.0f * b;                      // ||x-e||^2 expansion
            }
        }
        if (lane == 0) atomicAdd(diffsum, dsum);
    }
}

// new_cluster_size + its sum + diff finalize (single block).
__global__ __launch_bounds__(512) void k_ncs(const float* __restrict__ cluster_size,
                                             const float* __restrict__ ws,
                                             float* __restrict__ out,
                                             float* __restrict__ wsw) {
    __shared__ float red[512];
    int t = threadIdx.x;
    float ncs = cluster_size[t] * 0.99f + (1.0f - 0.99f) * ws[WS_CNT + t];
    out[OFF_NCS + t] = ncs;
    red[t] = ncs;
    __syncthreads();
    for (int off = 256; off > 0; off >>= 1) {
        if (t < off) red[t] += red[t + off];
        __syncthreads();
    }
    if (t == 0) {
        wsw[WS_NTOT] = red[0];
        out[OFF_DIFF] = ws[WS_DIFF] * (1.0f / 4194304.0f);
    }
}

// new_embed_avg + embed_new.
__global__ __launch_bounds__(512) void k_emb(const float* __restrict__ embed_avg,
                                             const float* __restrict__ ws,
                                             float* __restrict__ out) {
    int d = blockIdx.x;
    int t = threadIdx.x;
    float ncs = out[OFF_NCS + t];
    float ntot = ws[WS_NTOT];
    float csk = (ncs + 1e-5f) / (ntot + 512.0f * 1e-5f) * ntot;
    int idx = d * KC + t;
    float avg = embed_avg[idx] * 0.99f + (1.0f - 0.99f) * ws[WS_ESUM + t * 64 + d];
    out[OFF_NAVG + idx] = avg;
    out[OFF_ENEW + idx] = avg / csk;
}

extern "C" void kernel_launch(void* const* d_in, const int* in_sizes, int n_in,
                              void* d_out, int out_size, void* d_ws, size_t ws_size,
                              hipStream_t stream) {
    const float* input        = (const float*)d_in[0];
    const float* embed        = (const float*)d_in[1];
    const float* cluster_size = (const float*)d_in[2];
    const float* embed_avg    = (const float*)d_in[3];
    float* out = (float*)d_out;
    float* ws  = (float*)d_ws;

    k_prep<<<131, 256, 0, stream>>>(embed, ws);
    k_main<<<256, 512, 0, stream>>>(input, ws + WS_ET, ws + WS_C, out,
                                    ws + WS_CNT, ws + WS_ESUM, ws + WS_DIFF);
    k_ncs<<<1, 512, 0, stream>>>(cluster_size, ws, out, ws);
    k_emb<<<64, 512, 0, stream>>>(embed_avg, ws, out);
}

// Round 9
// 154.337 us; speedup vs baseline: 1.0187x; 1.0187x over previous
//
#include <hip/hip_runtime.h>

#define KC 512
#define NR 65536

// d_out layout (floats), reference return order:
// quantize_st[4194304], diff[1], embed_ind[65536], embed_new[32768],
// new_cluster_size[512], new_embed_avg[32768]
#define OFF_Q     0
#define OFF_DIFF  4194304
#define OFF_IND   4194305
#define OFF_ENEW  4259841
#define OFF_NCS   4292609
#define OFF_NAVG  4293121

// ws layout (floats)
#define WS_ET    0        // 32768: embed transposed [K][D]
#define WS_C     32768    // 512:   0.5*||e_k||^2
#define WS_CNT   33280    // 512:   one-hot counts
#define WS_ESUM  33792    // 32768: embed_sum transposed [K][D]
#define WS_DIFF  66560    // 1:     sum of squared diff
#define WS_NTOT  66561    // 1:     sum of new_cluster_size

// Prep: transpose embed [D][K] -> Et [K][D], code-norm bias, zero accumulators.
__global__ __launch_bounds__(256) void k_prep(const float* __restrict__ embed,
                                              float* __restrict__ ws) {
    int i = blockIdx.x * 256 + threadIdx.x;
    if (i < 512 + 32768 + 2) ws[WS_CNT + i] = 0.0f;   // counts, esum, diff, ntot
    if (i < 32768) {
        int k = i >> 6, d = i & 63;
        ws[WS_ET + i] = embed[d * KC + k];
    }
    if (i < 512) {
        float s = 0.0f;
        #pragma unroll
        for (int d = 0; d < 64; ++d) { float e = embed[d * KC + i]; s = fmaf(e, e, s); }
        ws[WS_C + i] = 0.5f * s;
    }
}

// Persistent register-tiled kernel. Grid = 256 blocks (1/CU), 512 thr = 8 waves.
// E^T (128 KB) staged once into XOR-swizzled LDS. Block loops 2 groups of 128
// rows; wave owns 16 rows/group; lane l owns codes {l+64j}, j=0..7.
// acc[16][8] (128 VGPR). Per dq-step per wave: 8 ds_read_b128 (each feeds 64
// FMAs) + 16 s_load_dwordx4 (x, wave-uniform) + 512 v_fma -> DS pipe ~37% of
// VALU time (was 75% at 8x8), lgkm drains amortized over 2x longer FMA burst.
// Per-code FP order identical to rounds 2-8 (-0.5||e||^2, d ascending).
__global__ __launch_bounds__(512, 2) void k_main(const float* __restrict__ input,
                                                 const float* __restrict__ Et,   // [512][64]
                                                 const float* __restrict__ c,
                                                 float* __restrict__ out,
                                                 float* __restrict__ counts,
                                                 float* __restrict__ esum,
                                                 float* __restrict__ diffsum) {
    __shared__ float4 EK4[8192];   // 128 KB: row k at [k*16], slot s stored at s^(k&15)

    const int t    = threadIdx.x;
    const int lane = t & 63;
    const int wave = __builtin_amdgcn_readfirstlane(t >> 6);  // 0..7, uniform
    const int sw   = lane & 15;

    // Stage swizzled E^T: ALL 8192 float4s (16 x 512).
    {
        const float4* Et4 = reinterpret_cast<const float4*>(Et);
        #pragma unroll
        for (int it = 0; it < 16; ++it) {
            int i = t + it * 512;
            int k = i >> 4, s = i & 15;
            EK4[k * 16 + (s ^ (k & 15))] = Et4[i];
        }
    }
    __syncthreads();

    // Per-lane code bias: codes c_j = lane + 64j.
    float negc[8];
    #pragma unroll
    for (int j = 0; j < 8; ++j) negc[j] = -c[lane + 64 * j];

    #pragma unroll 1
    for (int g = 0; g < 2; ++g) {
        const int row0 = blockIdx.x * 256 + g * 128 + wave * 16;

        float acc[16][8];
        #pragma unroll
        for (int r = 0; r < 16; ++r)
            #pragma unroll
            for (int j = 0; j < 8; ++j) acc[r][j] = negc[j];

        #pragma unroll 1
        for (int dq = 0; dq < 16; ++dq) {
            // E: 8 swizzled ds_read_b128, conflict-free (2 lanes/bank).
            float4 e4[8];
            #pragma unroll
            for (int j = 0; j < 8; ++j)
                e4[j] = EK4[(lane + 64 * j) * 16 + (dq ^ sw)];
            // x: wave-uniform -> s_load_dwordx4; 4 rows at a time.
            #pragma unroll
            for (int rr = 0; rr < 16; rr += 4) {
                float4 xr[4];
                #pragma unroll
                for (int r = 0; r < 4; ++r)
                    xr[r] = *reinterpret_cast<const float4*>(input + (size_t)(row0 + rr + r) * 64 + dq * 4);
                #pragma unroll
                for (int j = 0; j < 8; ++j) {
                    #pragma unroll
                    for (int r = 0; r < 4; ++r) {
                        acc[rr + r][j] = fmaf(xr[r].x, e4[j].x, acc[rr + r][j]);
                        acc[rr + r][j] = fmaf(xr[r].y, e4[j].y, acc[rr + r][j]);
                        acc[rr + r][j] = fmaf(xr[r].z, e4[j].z, acc[rr + r][j]);
                        acc[rr + r][j] = fmaf(xr[r].w, e4[j].w, acc[rr + r][j]);
                    }
                }
            }
        }

        // Per-row argmax (j ascending = k ascending; cross-lane lowest-k tie),
        // fused epilogue: quantize gather, EMA scatter, diff partials.
        float dsum = 0.0f;
        #pragma unroll
        for (int r = 0; r < 16; ++r) {
            float b = acc[r][0]; int bk = lane;
            #pragma unroll
            for (int j = 1; j < 8; ++j) {
                int cc = lane + 64 * j;
                if (acc[r][j] > b) { b = acc[r][j]; bk = cc; }
            }
            #pragma unroll
            for (int off = 1; off < 64; off <<= 1) {
                float vv = __shfl_xor(b, off);
                int   kk = __shfl_xor(bk, off);
                if (vv > b || (vv == b && kk < bk)) { b = vv; bk = kk; }
            }
            const int row = row0 + r;
            float e = Et[(size_t)bk * 64 + lane];          // 256 B coalesced gather
            out[OFF_Q + (size_t)row * 64 + lane] = e;
            float xv = input[(size_t)row * 64 + lane];
            atomicAdd(&esum[bk * 64 + lane], xv);
            float xs = xv * xv;
            #pragma unroll
            for (int off2 = 32; off2 > 0; off2 >>= 1) xs += __shfl_down(xs, off2);
            if (lane == 0) {
                out[OFF_IND + row] = (float)bk;
                atomicAdd(&counts[bk], 1.0f);
                dsum += xs - 2.0f * b;                      // ||x-e||^2 expansion
            }
        }
        if (lane == 0) atomicAdd(diffsum, dsum);
    }
}

// new_cluster_size + its sum + diff finalize (single block).
__global__ __launch_bounds__(512) void k_ncs(const float* __restrict__ cluster_size,
                                             const float* __restrict__ ws,
                                             float* __restrict__ out,
                                             float* __restrict__ wsw) {
    __shared__ float red[512];
    int t = threadIdx.x;
    float ncs = cluster_size[t] * 0.99f + (1.0f - 0.99f) * ws[WS_CNT + t];
    out[OFF_NCS + t] = ncs;
    red[t] = ncs;
    __syncthreads();
    for (int off = 256; off > 0; off >>= 1) {
        if (t < off) red[t] += red[t + off];
        __syncthreads();
    }
    if (t == 0) {
        wsw[WS_NTOT] = red[0];
        out[OFF_DIFF] = ws[WS_DIFF] * (1.0f / 4194304.0f);
    }
}

// new_embed_avg + embed_new.
__global__ __launch_bounds__(512) void k_emb(const float* __restrict__ embed_avg,
                                             const float* __restrict__ ws,
                                             float* __restrict__ out) {
    int d = blockIdx.x;
    int t = threadIdx.x;
    float ncs = out[OFF_NCS + t];
    float ntot = ws[WS_NTOT];
    float csk = (ncs + 1e-5f) / (ntot + 512.0f * 1e-5f) * ntot;
    int idx = d * KC + t;
    float avg = embed_avg[idx] * 0.99f + (1.0f - 0.99f) * ws[WS_ESUM + t * 64 + d];
    out[OFF_NAVG + idx] = avg;
    out[OFF_ENEW + idx] = avg / csk;
}

extern "C" void kernel_launch(void* const* d_in, const int* in_sizes, int n_in,
                              void* d_out, int out_size, void* d_ws, size_t ws_size,
                              hipStream_t stream) {
    const float* input        = (const float*)d_in[0];
    const float* embed        = (const float*)d_in[1];
    const float* cluster_size = (const float*)d_in[2];
    const float* embed_avg    = (const float*)d_in[3];
    float* out = (float*)d_out;
    float* ws  = (float*)d_ws;

    k_prep<<<131, 256, 0, stream>>>(embed, ws);
    k_main<<<256, 512, 0, stream>>>(input, ws + WS_ET, ws + WS_C, out,
                                    ws + WS_CNT, ws + WS_ESUM, ws + WS_DIFF);
    k_ncs<<<1, 512, 0, stream>>>(cluster_size, ws, out, ws);
    k_emb<<<64, 512, 0, stream>>>(embed_avg, ws, out);
}